// Round 7
// baseline (118.097 us; speedup 1.0000x reference)
//
#include <hip/hip_runtime.h>
#include <stdint.h>

typedef float f32x4 __attribute__((ext_vector_type(4)));
typedef __bf16 bf16x8 __attribute__((ext_vector_type(8)));
typedef __bf16 bf16x4 __attribute__((ext_vector_type(4)));

#define NROWS 65536     // 16 * 4096 x-rows
#define NCODES 4096
#define NDIM 64
#define NSPLIT 4        // code stripes (cross-block)
#define STEPS 32        // 1024 codes per stripe / 32 codes per step
#define SSTEP 4         // steps per barrier phase
#define PHASES (STEPS / SSTEP)  // 8

// ws layout (bytes):
//   [0x000000, 0x080000): codes bf16        4096*64*2 = 512 KB
//   [0x080000, 0x084000): nc2p paired -||c||^2/2: float2[2048]
//       pair index = stripe*512 + step*16 + col ; .x = code col, .y = col+16
//   [0x100000, 0x200000): tarr float[NROWS*NSPLIT]
//   [0x200000, 0x300000): marr int  [NROWS*NSPLIT]
//   [0x300000, 0x340000): x2   float[NROWS]

__device__ __forceinline__ void gld_lds16(const void* g, void* l) {
  __builtin_amdgcn_global_load_lds(
      (const __attribute__((address_space(1))) unsigned int*)g,
      (__attribute__((address_space(3))) unsigned int*)l, 16, 0, 0);
}

// Coalesced prep: 65536 threads, one f32x4 each; 16 lanes per code row.
// Writes bf16 codebook + paired -||c||^2/2 layout (see ws map).
__global__ __launch_bounds__(256) void prep_codes_k(const float* __restrict__ codes,
                                                    float* __restrict__ nc2p,
                                                    __bf16* __restrict__ cb) {
  const int t = blockIdx.x * 256 + threadIdx.x;  // 0..65535
  f32x4 v = *(const f32x4*)(codes + t * 4);
  bf16x4 o;
  float s = 0.f;
#pragma unroll
  for (int j = 0; j < 4; j++) {
    o[j] = (__bf16)v[j];
    s += v[j] * v[j];
  }
  *(bf16x4*)(cb + t * 4) = o;
  s += __shfl_xor(s, 1);
  s += __shfl_xor(s, 2);
  s += __shfl_xor(s, 4);
  s += __shfl_xor(s, 8);
  if ((threadIdx.x & 15) == 0) {
    const int c = t >> 4;  // code id 0..4095
    const int pidx = (c >> 10) * 512 + ((c >> 5) & 31) * 16 + (c & 15);
    const int half = (c >> 4) & 1;
    nc2p[pidx * 2 + half] = -0.5f * s;
  }
}

// Block = 256 thr = 4 waves sharing ONE 1024-code stripe through LDS; wave w
// owns 64 rows. Phase = 4 steps of 32 codes: stage 16KB once per phase
// (4x global_load_lds 16B per thread, XOR-pre-swizzled source), ONE barrier
// per phase (8 total vs 32). nc2 pairs live in LDS (ds_read_b64 per step).
// Swizzle involution (rule #21): LDS[P]=G[P^((P>>7&7)<<4)] on store, reader
// XORs the same -> identity; ds_read_b128 bank-spread. Block mapping:
// stripe=bid>>8, rowgrp=bid&255 -> the 4 blocks of a rowgrp are bids
// {r,r+256,r+512,r+768}, all same XCD (mod 8) -> x slice L2-resident.
// A-frag (mfma_f32_16x16x32_bf16): lane holds A[m=lane&15][k=quad*8+j].
// C/D: col(n)=lane&15, row(m)=quad*4+reg (m89/m91-verified).
// MFMA C-init = -||c||^2/2 so acc = dot - c2/2; argmax(acc)==argmin d2;
// d2 = x2 - 2*acc (exact *2). Strict '>' + ascending order => lowest index.
__global__ __launch_bounds__(256, 4) void nn_main(const float* __restrict__ x,
                                                  const __bf16* __restrict__ cbv,
                                                  const float2* __restrict__ nc2p,
                                                  float* __restrict__ tarr,
                                                  int* __restrict__ marr,
                                                  float* __restrict__ x2arr) {
  const int tid  = threadIdx.x;
  const int lane = tid & 63;
  const int w    = tid >> 6;   // wave id = row chunk
  const int col  = lane & 15;
  const int quad = lane >> 4;
  const int stripe = blockIdx.x >> 8;      // 0..3
  const int rowgrp = blockIdx.x & 255;     // 0..255
  const int rowbase = rowgrp * 256 + w * 64;
  const char* cbb = (const char*)cbv;

  __shared__ __align__(16) char stage[2][SSTEP * 4096];  // 32 KB
  __shared__ __align__(8) float2 ncl[512];               // 4 KB: [step][col]

  // ---- stage this stripe's nc2 pairs (4 KB) + phase 0 (16 KB) ----
  const uint32_t schunk = ((uint32_t)(tid * 16)) ^ ((((uint32_t)tid >> 3) & 7u) << 4);
  const char* srcbase = cbb + (uint32_t)stripe * 131072u + schunk;
  gld_lds16((const char*)nc2p + stripe * 4096 + tid * 16, (char*)ncl + w * 1024);
#pragma unroll
  for (int i = 0; i < SSTEP; i++)
    gld_lds16(srcbase + i * 4096, &stage[0][i * 4096 + w * 1024]);

  // ---- A fragments (fp32 -> bf16) + ||x||^2 (overlaps with stages) ----
  bf16x8 a[4][2];
  float x2part[4];
#pragma unroll
  for (int rt = 0; rt < 4; rt++) {
    const float* xr = x + (rowbase + rt * 16 + col) * NDIM + quad * 8;
    float p = 0.f;
#pragma unroll
    for (int kc = 0; kc < 2; kc++) {
      f32x4 v0 = *(const f32x4*)(xr + kc * 32);
      f32x4 v1 = *(const f32x4*)(xr + kc * 32 + 4);
      bf16x8 af;
#pragma unroll
      for (int j = 0; j < 4; j++) {
        af[j]     = (__bf16)v0[j];
        af[j + 4] = (__bf16)v1[j];
        p += v0[j] * v0[j] + v1[j] * v1[j];
      }
      a[rt][kc] = af;
    }
    x2part[rt] = p;
  }
#pragma unroll
  for (int rt = 0; rt < 4; rt++) {
    float p = x2part[rt];
    p += __shfl_xor(p, 16);
    p += __shfl_xor(p, 32);
    x2part[rt] = p;
  }
  if (stripe == 0 && quad == 0) {
#pragma unroll
    for (int rt = 0; rt < 4; rt++) x2arr[rowbase + rt * 16 + col] = x2part[rt];
  }

  float bestT[4][4];
  int bestM[4][4];
#pragma unroll
  for (int rt = 0; rt < 4; rt++)
#pragma unroll
    for (int j = 0; j < 4; j++) {
      bestT[rt][j] = -3.0e38f;
      bestM[rt][j] = 0;
    }

  // ---- reader LDS byte offsets (swizzled), within a 4KB tile ----
  const uint32_t swz = ((uint32_t)(col & 7)) << 4;
  const uint32_t o00 = ((uint32_t)(col * 128 + quad * 16)) ^ swz;
  const uint32_t o01 = ((uint32_t)(col * 128 + 64 + quad * 16)) ^ swz;
  const uint32_t o10 = ((uint32_t)(2048 + col * 128 + quad * 16)) ^ swz;
  const uint32_t o11 = ((uint32_t)(2048 + col * 128 + 64 + quad * 16)) ^ swz;

  const int mibase = stripe * 1024 + col;

  __syncthreads();  // ncl + phase 0 staged

#pragma unroll 1
  for (int p = 0; p < PHASES; ++p) {
    // prefetch next phase into the other buffer (in flight across this phase)
    if (p < PHASES - 1) {
      const char* sp = srcbase + (p + 1) * (SSTEP * 4096);
      char* dst = &stage[(p + 1) & 1][w * 1024];
#pragma unroll
      for (int i = 0; i < SSTEP; i++) gld_lds16(sp + i * 4096, dst + i * 4096);
    }
    const char* sb = stage[p & 1];
#pragma unroll
    for (int ss = 0; ss < SSTEP; ss++) {
      const int s = p * SSTEP + ss;  // global step 0..31
      const float2 nv = ncl[s * 16 + col];
      bf16x8 b00 = *(const bf16x8*)(sb + ss * 4096 + o00);
      bf16x8 b01 = *(const bf16x8*)(sb + ss * 4096 + o01);
      bf16x8 b10 = *(const bf16x8*)(sb + ss * 4096 + o10);
      bf16x8 b11 = *(const bf16x8*)(sb + ss * 4096 + o11);
      f32x4 ci0 = {nv.x, nv.x, nv.x, nv.x};
      f32x4 ci1 = {nv.y, nv.y, nv.y, nv.y};
      const int mi0 = mibase + s * 32;
      const int mi1 = mi0 + 16;
#pragma unroll
      for (int rt = 0; rt < 4; rt++) {
        f32x4 acc0 = __builtin_amdgcn_mfma_f32_16x16x32_bf16(a[rt][0], b00, ci0, 0, 0, 0);
        acc0 = __builtin_amdgcn_mfma_f32_16x16x32_bf16(a[rt][1], b01, acc0, 0, 0, 0);
        f32x4 acc1 = __builtin_amdgcn_mfma_f32_16x16x32_bf16(a[rt][0], b10, ci1, 0, 0, 0);
        acc1 = __builtin_amdgcn_mfma_f32_16x16x32_bf16(a[rt][1], b11, acc1, 0, 0, 0);
#pragma unroll
        for (int j = 0; j < 4; j++) {
          if (acc0[j] > bestT[rt][j]) { bestT[rt][j] = acc0[j]; bestM[rt][j] = mi0; }
          if (acc1[j] > bestT[rt][j]) { bestT[rt][j] = acc1[j]; bestM[rt][j] = mi1; }
        }
      }
    }
    __syncthreads();  // next buffer staged; this buffer free
  }

  // ---- butterfly argmax across the 16 lanes sharing each row; write partials ----
#pragma unroll
  for (int rt = 0; rt < 4; rt++) {
#pragma unroll
    for (int j = 0; j < 4; j++) {
      float bt = bestT[rt][j];
      int bm = bestM[rt][j];
#pragma unroll
      for (int off = 1; off < 16; off <<= 1) {
        float ot = __shfl_xor(bt, off);
        int om = __shfl_xor(bm, off);
        if (ot > bt || (ot == bt && om < bm)) {
          bt = ot;
          bm = om;
        }
      }
      if (col == 0) {
        const int row = rowbase + rt * 16 + quad * 4 + j;
        tarr[row * NSPLIT + stripe] = bt;
        marr[row * NSPLIT + stripe] = bm;
      }
    }
  }
}

__global__ __launch_bounds__(256) void nn_final(const float* __restrict__ tarr,
                                                const int* __restrict__ marr,
                                                const float* __restrict__ x2arr,
                                                int* __restrict__ out) {
  const int row = blockIdx.x * blockDim.x + threadIdx.x;
  if (row >= NROWS) return;
  float bt = tarr[row * NSPLIT];
  int bm = marr[row * NSPLIT];
#pragma unroll
  for (int s = 1; s < NSPLIT; s++) {
    float t = tarr[row * NSPLIT + s];
    int m = marr[row * NSPLIT + s];
    if (t > bt || (t == bt && m < bm)) {
      bt = t;
      bm = m;
    }
  }
  const float d2 = fmaf(-2.0f, bt, x2arr[row]);  // min squared distance
  out[row] = (d2 <= 0.1f) ? bm : -1;
}

extern "C" void kernel_launch(void* const* d_in, const int* in_sizes, int n_in,
                              void* d_out, int out_size, void* d_ws, size_t ws_size,
                              hipStream_t stream) {
  const float* x = (const float*)d_in[0];      // [65536][64] fp32
  const float* codes = (const float*)d_in[1];  // [4096][64] fp32
  int* out = (int*)d_out;                      // [65536] int32

  char* ws = (char*)d_ws;
  __bf16* cb = (__bf16*)ws;                     // 512 KB
  float* nc2p = (float*)(ws + 0x080000);        // 16 KB (float2[2048])
  float* tarr = (float*)(ws + 0x100000);        // 1 MB
  int* marr = (int*)(ws + 0x200000);            // 1 MB
  float* x2arr = (float*)(ws + 0x300000);       // 256 KB

  prep_codes_k<<<256, 256, 0, stream>>>(codes, nc2p, cb);
  nn_main<<<1024, 256, 0, stream>>>(x, cb, (const float2*)nc2p, tarr, marr, x2arr);
  nn_final<<<256, 256, 0, stream>>>(tarr, marr, x2arr, out);
}